// Round 1
// baseline (507.849 us; speedup 1.0000x reference)
//
#include <hip/hip_runtime.h>
#include <stdint.h>

#define N_NODES 8192
#define CH 256
#define MT 32
#define BK 64
#define KB_COUNT (N_NODES / BK)  // 128

typedef __bf16 bf16x8 __attribute__((ext_vector_type(8)));
typedef float f32x4 __attribute__((ext_vector_type(4)));
typedef unsigned int u32x4 __attribute__((ext_vector_type(4)));

// ---- async global->LDS, 16B per lane. LDS dest must be the WAVE-UNIFORM base;
// HW scatters lane l to base + 16*l. AS casts via integer (generic->AS3 = low 32 bits).
__device__ __forceinline__ void async_copy16(const void* g, void* l) {
  __builtin_amdgcn_global_load_lds(
      (const __attribute__((address_space(1))) void*)(uintptr_t)g,
      (__attribute__((address_space(3))) void*)(uint32_t)(uintptr_t)l,
      16, 0, 0);
}

__device__ __forceinline__ unsigned short f32_to_bf16_rne(float f) {
  unsigned u = __float_as_uint(f);
  u += 0x7FFFu + ((u >> 16) & 1u);
  return (unsigned short)(u >> 16);
}

// ---------------- K1: deg = rowsum(adj) + 1 ; dsq = rsqrt(deg) ----------------
__global__ void __launch_bounds__(256) k_deg(const float* __restrict__ adj,
                                             float* __restrict__ dsq) {
  __shared__ float red[256];
  const int row = blockIdx.x;
  const f32x4* ar = (const f32x4*)(adj + (size_t)row * N_NODES);
  float s = 0.f;
#pragma unroll
  for (int i = 0; i < 8; ++i) {
    f32x4 v = ar[threadIdx.x + 256 * i];
    s += (v.x + v.y) + (v.z + v.w);
  }
  red[threadIdx.x] = s;
  __syncthreads();
  for (int st = 128; st > 0; st >>= 1) {
    if (threadIdx.x < (unsigned)st) red[threadIdx.x] += red[threadIdx.x + st];
    __syncthreads();
  }
  if (threadIdx.x == 0) dsq[row] = rsqrtf(red[0] + 1.0f);
}

// ------------- K2: y_t[c][j] = bf16(dsq[j] * x[j][c])  (transposed) -----------
__global__ void __launch_bounds__(256) k_ytrans(const float* __restrict__ x,
                                                const float* __restrict__ dsq,
                                                unsigned short* __restrict__ yt) {
  __shared__ float tile[64][65];
  __shared__ float ds_s[64];
  const int j0 = blockIdx.x * 64, c0 = blockIdx.y * 64;
  const int t = threadIdx.x;
  const int lc = t & 63, lr4 = t >> 6;  // lr4 in 0..3
  if (t < 64) ds_s[t] = dsq[j0 + t];
  __syncthreads();
#pragma unroll
  for (int rr = 0; rr < 16; ++rr) {
    int jr = rr * 4 + lr4;
    tile[jr][lc] = x[(size_t)(j0 + jr) * CH + c0 + lc] * ds_s[jr];
  }
  __syncthreads();
#pragma unroll
  for (int rr = 0; rr < 16; ++rr) {
    int cr = rr * 4 + lr4;
    yt[(size_t)(c0 + cr) * N_NODES + j0 + lc] = f32_to_bf16_rne(tile[lc][cr]);
  }
}

// ---------------- K3: S = adj @ y ; h = dsq_i*(S + dsq_i*x) -> d_out ----------
// Tile: 32 rows x 256 cols, full K. 4 waves split N (64 cols each).
// LDS (double buffered): A fp32 [32][64] (8KB), B bf16 [256][64] (32KB), XOR-swizzled
// at 16B-chunk granularity so frag ds_read_b128 is <=2-way bank conflict (free).
__global__ void __launch_bounds__(256, 1) k_gemm1(const float* __restrict__ adj,
                                                  const unsigned short* __restrict__ yt,
                                                  const float* __restrict__ x,
                                                  const float* __restrict__ dsq,
                                                  float* __restrict__ hout) {
  __shared__ __align__(16) float As[2][MT * BK];           // 8 KB each
  __shared__ __align__(16) unsigned short Bs[2][CH * BK];  // 32 KB each

  const int tid = threadIdx.x;
  const int wave = tid >> 6;
  const int lane = tid & 63;
  const int m0 = blockIdx.x * MT;
  const int lr = lane & 15;  // row/col within 16
  const int lq = lane >> 4;  // quad 0..3

  // A staging: 8 wave-instrs total, 2 per wave. instr i covers chunks s=64i+l.
  // chunk s -> (row = s>>4, swizzled c16 = (s&15)); global c16 = (l&15)^(row&15).
  const float* ag[2];
  int aoffu[2];  // wave-uniform LDS byte base per instr
#pragma unroll
  for (int q = 0; q < 2; ++q) {
    int i = wave * 2 + q;
    int s = 64 * i + lane;
    int row = s >> 4;
    int c16 = (lane & 15) ^ (row & 15);
    ag[q] = adj + (size_t)(m0 + row) * N_NODES + c16 * 4;
    aoffu[q] = 64 * i * 16;
  }
  // B staging: 32 wave-instrs, 8 per wave. chunk s -> (n = s>>3, x=s&7); c8=(l&7)^(n&7).
  const unsigned short* bg[8];
  int boffu[8];
#pragma unroll
  for (int q = 0; q < 8; ++q) {
    int i = wave * 8 + q;
    int s = 64 * i + lane;
    int n = s >> 3;
    int c8 = (lane & 7) ^ (n & 7);
    bg[q] = yt + (size_t)n * N_NODES + c8 * 8;
    boffu[q] = 64 * i * 16;
  }

  f32x4 acc[2][4];
#pragma unroll
  for (int i = 0; i < 2; ++i)
#pragma unroll
    for (int j = 0; j < 4; ++j) acc[i][j] = (f32x4){0.f, 0.f, 0.f, 0.f};

  auto issue = [&](int b, int k0) {
    char* aL = (char*)&As[b][0];
    char* bL = (char*)&Bs[b][0];
#pragma unroll
    for (int q = 0; q < 2; ++q) async_copy16(ag[q] + k0, aL + aoffu[q]);
#pragma unroll
    for (int q = 0; q < 8; ++q) async_copy16(bg[q] + k0, bL + boffu[q]);
  };

  issue(0, 0);

  for (int kb = 0; kb < KB_COUNT; ++kb) {
    const int b = kb & 1;
    if (kb + 1 < KB_COUNT) {
      issue(b ^ 1, (kb + 1) * BK);
      // wait only for buffer b's 10 loads (ours); next 10 stay in flight
      asm volatile("s_waitcnt vmcnt(10)\n\ts_barrier" ::: "memory");
    } else {
      asm volatile("s_waitcnt vmcnt(0)\n\ts_barrier" ::: "memory");
    }

    const char* aB = (const char*)&As[b][0];
    const char* bB = (const char*)&Bs[b][0];

#pragma unroll
    for (int k32 = 0; k32 < 2; ++k32) {
      bf16x8 afr[2];
#pragma unroll
      for (int mt = 0; mt < 2; ++mt) {
        int row = mt * 16 + lr;
        int c16 = k32 * 8 + lq * 2;
        int s0 = row * 16 + ((c16) ^ (row & 15));
        int s1 = row * 16 + ((c16 + 1) ^ (row & 15));
        f32x4 r0 = *(const f32x4*)(aB + s0 * 16);
        f32x4 r1 = *(const f32x4*)(aB + s1 * 16);
        u32x4 pk;
        pk.x = __builtin_amdgcn_perm(__float_as_uint(r0.y), __float_as_uint(r0.x), 0x07060302u);
        pk.y = __builtin_amdgcn_perm(__float_as_uint(r0.w), __float_as_uint(r0.z), 0x07060302u);
        pk.z = __builtin_amdgcn_perm(__float_as_uint(r1.y), __float_as_uint(r1.x), 0x07060302u);
        pk.w = __builtin_amdgcn_perm(__float_as_uint(r1.w), __float_as_uint(r1.z), 0x07060302u);
        afr[mt] = __builtin_bit_cast(bf16x8, pk);
      }
#pragma unroll
      for (int nt = 0; nt < 4; ++nt) {
        int n = wave * 64 + nt * 16 + lr;
        int c8 = k32 * 4 + lq;
        int s = n * 8 + (c8 ^ (n & 7));
        bf16x8 bfr = *(const bf16x8*)(bB + s * 16);
        acc[0][nt] = __builtin_amdgcn_mfma_f32_16x16x32_bf16(afr[0], bfr, acc[0][nt], 0, 0, 0);
        acc[1][nt] = __builtin_amdgcn_mfma_f32_16x16x32_bf16(afr[1], bfr, acc[1][nt], 0, 0, 0);
      }
    }
    // LDS reads drained before next iter's async loads overwrite buffer b^1
    asm volatile("s_waitcnt lgkmcnt(0)\n\ts_barrier" ::: "memory");
  }

  // epilogue: h[i][c] = dsq_i * (acc + dsq_i * x[i][c])
#pragma unroll
  for (int mt = 0; mt < 2; ++mt) {
#pragma unroll
    for (int r = 0; r < 4; ++r) {
      int row = m0 + mt * 16 + lq * 4 + r;
      float di = dsq[row];
#pragma unroll
      for (int nt = 0; nt < 4; ++nt) {
        int col = wave * 64 + nt * 16 + lr;
        float v = acc[mt][nt][r];
        v = di * (v + di * x[(size_t)row * CH + col]);
        hout[(size_t)row * CH + col] = v;
      }
    }
  }
}

// ---------------- K4: out = elu(h @ w), in place on d_out ----------------
__global__ void __launch_bounds__(256) k_gemm2(float* __restrict__ h,
                                               const float* __restrict__ w) {
  __shared__ __align__(16) float hs[16][CH];
  const int r0 = blockIdx.x * 16;
  const int t = threadIdx.x;
#pragma unroll
  for (int i = 0; i < 16; ++i) hs[i][t] = h[(size_t)(r0 + i) * CH + t];
  __syncthreads();
  float acc[16];
#pragma unroll
  for (int r = 0; r < 16; ++r) acc[r] = 0.f;
  for (int k = 0; k < CH; k += 4) {
    float w0 = w[(k + 0) * CH + t];
    float w1 = w[(k + 1) * CH + t];
    float w2 = w[(k + 2) * CH + t];
    float w3 = w[(k + 3) * CH + t];
#pragma unroll
    for (int r = 0; r < 16; ++r) {
      f32x4 hv = *(const f32x4*)&hs[r][k];
      acc[r] += hv.x * w0 + hv.y * w1 + hv.z * w2 + hv.w * w3;
    }
  }
#pragma unroll
  for (int r = 0; r < 16; ++r) {
    float v = acc[r];
    v = v > 0.f ? v : expm1f(v);
    h[(size_t)(r0 + r) * CH + t] = v;
  }
}

extern "C" void kernel_launch(void* const* d_in, const int* in_sizes, int n_in,
                              void* d_out, int out_size, void* d_ws, size_t ws_size,
                              hipStream_t stream) {
  const float* x = (const float*)d_in[0];
  const float* adj = (const float*)d_in[1];
  const float* w = (const float*)d_in[2];
  float* out = (float*)d_out;

  // ws layout: dsq [8192 f32] @0 ; y_t [256][8192] bf16 @32KB  (total ~4.03 MB)
  float* dsq = (float*)d_ws;
  unsigned short* yt = (unsigned short*)((char*)d_ws + 32768);

  k_deg<<<N_NODES, 256, 0, stream>>>(adj, dsq);
  k_ytrans<<<dim3(N_NODES / 64, CH / 64), 256, 0, stream>>>(x, dsq, yt);
  k_gemm1<<<N_NODES / MT, 256, 0, stream>>>(adj, yt, x, dsq, out);
  k_gemm2<<<N_NODES / 16, 256, 0, stream>>>(out, w);
}